// Round 3
// baseline (378.876 us; speedup 1.0000x reference)
//
#include <hip/hip_runtime.h>
#include <math.h>

#define EPS_GS 1e-8f
#define RAD2DEG 57.29577951308232f
#define PI_F 3.14159265358979f

constexpr int THREADS   = 256;
constexpr int TILE_ROTS = 512;                    // rotations per tile
constexpr int TILE_F    = TILE_ROTS * 9;          // 4608 floats = 18432 B per array
constexpr int TILE_F2   = TILE_F / 2;             // 2304 float2
constexpr int F2_PER_TH = TILE_F2 / THREADS;      // 9
constexpr int NSLOTS    = 16;                     // atomic spread slots (64B stride)
constexpr int MAX_BLKS  = 1024;                   // 4 resident blocks x 256 CUs

__device__ __forceinline__ float clip10(float x) {
    // ternary form preserves NaN (matches jnp.clip NaN propagation)
    x = x < -10.f ? -10.f : x;
    x = x >  10.f ?  10.f : x;
    return x;
}

// v_sqrt_f32 / v_rcp_f32 — ~1 ulp, single-instruction
__device__ __forceinline__ float fsqrt(float x) { return __builtin_amdgcn_sqrtf(x); }
__device__ __forceinline__ float frcp(float x)  { return __builtin_amdgcn_rcpf(x); }

// Abramowitz-Stegun 4.4.45: max error 6.76e-5 rad on [-1,1]
__device__ __forceinline__ float fast_acos(float x) {
    float ax = fabsf(x);
    float p = fmaf(ax, -0.0187293f, 0.0742610f);
    p = fmaf(ax, p, -0.2121144f);
    p = fmaf(ax, p, 1.5707288f);
    float pos = fsqrt(1.f - ax) * p;
    return x >= 0.f ? pos : PI_F - pos;
}

// v: 3x3 row-major (clipped). Columns: c0=(v0,v3,v6), c1=(v1,v4,v7), c2=(v2,v5,v8).
// R: row-major rotation, columns e1,e2,e3 (e3 sign-fixed by det).
__device__ __forceinline__ void gs_rotmat(const float* v, float* R) {
    float c0x = v[0], c0y = v[3], c0z = v[6];
    float c1x = v[1], c1y = v[4], c1z = v[7];
    float c2x = v[2], c2y = v[5], c2z = v[8];

    float s1 = fmaf(c0x, c0x, fmaf(c0y, c0y, c0z*c0z));
    float inv1 = frcp(fsqrt(s1) + EPS_GS);
    float e1x = c0x*inv1, e1y = c0y*inv1, e1z = c0z*inv1;

    float d = fmaf(e1x, c1x, fmaf(e1y, c1y, e1z*c1z));
    float u2x = fmaf(-d, e1x, c1x), u2y = fmaf(-d, e1y, c1y), u2z = fmaf(-d, e1z, c1z);
    float s2 = fmaf(u2x, u2x, fmaf(u2y, u2y, u2z*u2z));
    float inv2 = frcp(fsqrt(s2) + EPS_GS);
    float e2x = u2x*inv2, e2y = u2y*inv2, e2z = u2z*inv2;

    float d1 = fmaf(e1x, c2x, fmaf(e1y, c2y, e1z*c2z));
    float d2 = fmaf(e2x, c2x, fmaf(e2y, c2y, e2z*c2z));
    float u3x = fmaf(-d1, e1x, fmaf(-d2, e2x, c2x));
    float u3y = fmaf(-d1, e1y, fmaf(-d2, e2y, c2y));
    float u3z = fmaf(-d1, e1z, fmaf(-d2, e2z, c2z));
    float s3 = fmaf(u3x, u3x, fmaf(u3y, u3y, u3z*u3z));
    float inv3 = frcp(fsqrt(s3) + EPS_GS);
    float e3x = u3x*inv3, e3y = u3y*inv3, e3z = u3z*inv3;

    // det(Q) = e1 . (e2 x e3)
    float cxx = e2y*e3z - e2z*e3y;
    float cxy = e2z*e3x - e2x*e3z;
    float cxz = e2x*e3y - e2y*e3x;
    float det = fmaf(e1x, cxx, fmaf(e1y, cxy, e1z*cxz));
    if (det < 0.f) { e3x = -e3x; e3y = -e3y; e3z = -e3z; } // NaN<0 false -> keep

    R[0] = e1x; R[1] = e2x; R[2] = e3x;
    R[3] = e1y; R[4] = e2y; R[5] = e3y;
    R[6] = e1z; R[7] = e2z; R[8] = e3z;
}

__device__ __forceinline__ void accum_rot(const float* pr, const float* tg,
                                          float& lt, float& lf) {
    float pc[9], tc[9];
    #pragma unroll
    for (int m = 0; m < 9; ++m) { pc[m] = clip10(pr[m]); tc[m] = clip10(tg[m]); }

    float Rp[9], Rt[9];
    gs_rotmat(pc, Rp);
    gs_rotmat(tc, Rt);

    float chord = 0.f, tr = 0.f;
    #pragma unroll
    for (int m = 0; m < 9; ++m) {
        float d = Rp[m] - Rt[m];
        chord = fmaf(d, d, chord);
        tr    = fmaf(Rp[m], Rt[m], tr);
    }

    const float trLo = -3.0f + 1e-6f, trHi = 3.0f - 1e-6f;
    tr = tr < trLo ? trLo : (tr > trHi ? trHi : tr);
    float ca = (tr - 1.f) * 0.5f;
    const float cLo = -1.0f + 1e-7f, cHi = 1.0f - 1e-7f;
    ca = ca < cLo ? cLo : (ca > cHi ? cHi : ca);
    float ang = fast_acos(ca) * RAD2DEG;
    if (ang != ang) ang = 180.f;

    // orthogonality: AtA[i][j] = col_i . col_j of clipped pred matrix.
    // AtA symmetric: diag once, off-diag counted twice.
    float o = 0.f;
    #pragma unroll
    for (int i = 0; i < 3; ++i) {
        float dii = fmaf(pc[i], pc[i], fmaf(pc[3+i], pc[3+i], pc[6+i]*pc[6+i])) - 1.f;
        o = fmaf(dii, dii, o);
    }
    #pragma unroll
    for (int i = 0; i < 3; ++i) {
        #pragma unroll
        for (int j = i + 1; j < 3; ++j) {
            float s = fmaf(pc[i], pc[j], fmaf(pc[3+i], pc[3+j], pc[6+i]*pc[6+j]));
            float s2 = s + s;
            o = fmaf(s2, s, o);
        }
    }

    float l2 = 0.f, fb = 0.f;
    #pragma unroll
    for (int m = 0; m < 9; ++m) {
        l2 = fmaf(pc[m], pc[m], l2);
        float d = pc[m] - tg[m];   // fallback uses UNclipped target
        fb = fmaf(d, d, fb);
    }

    lt += fmaf(0.1f, ang, chord) + fmaf(0.01f, o, (1e-4f/9.f)*l2);
    lf += fb;
}

// Grid-stride software-pipelined version.
// Per tile: ds_write(prefetched regs) -> barrier -> ISSUE next tile's coalesced
// loads -> compute current tile from LDS -> barrier. The ~900cy HBM latency of
// tile t+1 hides under tile t's ~1300cy compute phase, decoupling the memory
// and VALU pipes that were ping-ponging (r2: VALUBusy 26%, HBM 15%).
__global__ __launch_bounds__(THREADS, 4)
void rot_loss_kernel(const float* __restrict__ pred, const float* __restrict__ targ,
                     double* __restrict__ acc, int B) {
    __shared__ float sp[TILE_F];
    __shared__ float sq[TILE_F];
    __shared__ float rsum_t[4], rsum_f[4];

    const int tid    = threadIdx.x;
    const int ntiles = (B + TILE_ROTS - 1) / TILE_ROTS;

    float lt = 0.f, lf = 0.f;

    float2 pv[F2_PER_TH], tv[F2_PER_TH];

    auto issue_loads = [&](int t) {
        const float2* p2 = reinterpret_cast<const float2*>(pred) + (size_t)t * TILE_F2;
        const float2* q2 = reinterpret_cast<const float2*>(targ) + (size_t)t * TILE_F2;
        #pragma unroll
        for (int k = 0; k < F2_PER_TH; ++k) pv[k] = p2[tid + k*THREADS];
        #pragma unroll
        for (int k = 0; k < F2_PER_TH; ++k) tv[k] = q2[tid + k*THREADS];
    };
    auto tile_full = [&](int t) {
        return (size_t)(t + 1) * TILE_ROTS <= (size_t)B;
    };

    int t0 = blockIdx.x;
    if (t0 < ntiles && tile_full(t0)) issue_loads(t0);   // prologue prefetch

    for (int t = t0; t < ntiles; t += gridDim.x) {
        const size_t rot0 = (size_t)t * TILE_ROTS;
        if (tile_full(t)) {
            // regs -> LDS (compiler places the vmcnt wait here)
            float2* sp2 = reinterpret_cast<float2*>(sp);
            float2* sq2 = reinterpret_cast<float2*>(sq);
            #pragma unroll
            for (int k = 0; k < F2_PER_TH; ++k) {
                sp2[tid + k*THREADS] = pv[k];
                sq2[tid + k*THREADS] = tv[k];
            }
            __syncthreads();
            // prefetch the NEXT full tile this block will process
            const int tn = t + gridDim.x;
            if (tn < ntiles && tile_full(tn)) issue_loads(tn);
            // compute current tile from LDS (9-dword row stride: gcd(9,32)=1
            // -> 2 lanes/bank, conflict-free; r2 counter confirmed 0)
            #pragma unroll
            for (int rr = 0; rr < 2; ++rr) {
                const int r = tid + rr*THREADS;
                accum_rot(&sp[9*r], &sq[9*r], lt, lf);
            }
            __syncthreads();   // LDS free for next overwrite
        } else {
            // partial tail tile: direct loads, correctness only
            const int rem = (int)((size_t)B - rot0);
            for (int r = tid; r < rem; r += THREADS) {
                float a1[9], b1[9];
                const float* pp = pred + (rot0 + r) * 9;
                const float* qq = targ + (rot0 + r) * 9;
                for (int m = 0; m < 9; ++m) { a1[m] = pp[m]; b1[m] = qq[m]; }
                accum_rot(a1, b1, lt, lf);
            }
        }
    }

    // wave-64 reduce
    #pragma unroll
    for (int off = 32; off > 0; off >>= 1) {
        lt += __shfl_down(lt, off, 64);
        lf += __shfl_down(lf, off, 64);
    }
    const int lane = tid & 63;
    const int wid  = tid >> 6;
    if (lane == 0) { rsum_t[wid] = lt; rsum_f[wid] = lf; }
    __syncthreads();
    if (tid == 0) {
        float bt = rsum_t[0] + rsum_t[1] + rsum_t[2] + rsum_t[3];
        float bf = rsum_f[0] + rsum_f[1] + rsum_f[2] + rsum_f[3];
        // spread atomics over 16 cache-line-strided slots to avoid
        // same-address f64 atomic serialization at the coherence point
        double* slot = acc + (size_t)(blockIdx.x & (NSLOTS - 1)) * 8;
        unsafeAtomicAdd(&slot[0], (double)bt);  // HW global_atomic_add_f64
        unsafeAtomicAdd(&slot[1], (double)bf);
    }
}

__global__ void finalize_kernel(const double* __restrict__ acc,
                                float* __restrict__ out, int B) {
    if (threadIdx.x == 0 && blockIdx.x == 0) {
        double t = 0.0, f = 0.0;
        for (int s = 0; s < NSLOTS; ++s) { t += acc[s*8]; f += acc[s*8 + 1]; }
        double total = t / (double)B;
        double fb    = f / (9.0 * (double)B);
        out[0] = isnan(total) ? (float)fb : (float)total;
    }
}

extern "C" void kernel_launch(void* const* d_in, const int* in_sizes, int n_in,
                              void* d_out, int out_size, void* d_ws, size_t ws_size,
                              hipStream_t stream) {
    const float* pred = (const float*)d_in[0];
    const float* targ = (const float*)d_in[1];
    const int n = in_sizes[0];
    const int B = n / 9;

    double* acc = (double*)d_ws;
    hipMemsetAsync(d_ws, 0, NSLOTS * 8 * sizeof(double), stream);

    const int ntiles = (B + TILE_ROTS - 1) / TILE_ROTS;
    const int blocks = ntiles < MAX_BLKS ? ntiles : MAX_BLKS;
    rot_loss_kernel<<<blocks, THREADS, 0, stream>>>(pred, targ, acc, B);
    finalize_kernel<<<1, 64, 0, stream>>>(acc, (float*)d_out, B);
}

// Round 4
// 316.912 us; speedup vs baseline: 1.1955x; 1.1955x over previous
//
#include <hip/hip_runtime.h>
#include <math.h>

#define EPS_GS 1e-8f
#define RAD2DEG 57.29577951308232f
#define PI_F 3.14159265358979f

constexpr int THREADS   = 256;
constexpr int TILE_ROTS = 512;                    // rotations per tile
constexpr int TILE_F    = TILE_ROTS * 9;          // 4608 floats = 18432 B per array
constexpr int TILE_TOT  = TILE_F * 2;             // pred+targ = 9216 floats / tile
constexpr int CHUNK_F   = 256;                    // floats per 1024B chunk (64 lanes x 16B)
constexpr int CHUNKS    = TILE_TOT / CHUNK_F;     // 36 chunks per tile
constexpr int CH_PER_W  = CHUNKS / 4;             // 9 async loads per wave per tile
constexpr int NSLOTS    = 16;                     // atomic spread slots (64B stride)
constexpr int MAX_BLKS  = 512;                    // 2 resident blocks x 256 CUs (LDS-limited)

__device__ __forceinline__ float clip10(float x) {
    // ternary form preserves NaN (matches jnp.clip NaN propagation)
    x = x < -10.f ? -10.f : x;
    x = x >  10.f ?  10.f : x;
    return x;
}

// v_sqrt_f32 / v_rcp_f32 — ~1 ulp, single-instruction
__device__ __forceinline__ float fsqrt(float x) { return __builtin_amdgcn_sqrtf(x); }
__device__ __forceinline__ float frcp(float x)  { return __builtin_amdgcn_rcpf(x); }

// async global->LDS, 16B per lane. LDS dest = wave-uniform base + lane*16.
__device__ __forceinline__ void gload_lds16(const float* g, float* l) {
    __builtin_amdgcn_global_load_lds(
        (const __attribute__((address_space(1))) void*)g,
        (__attribute__((address_space(3))) void*)l,
        16, 0, 0);
}

// Abramowitz-Stegun 4.4.45: max error 6.76e-5 rad on [-1,1]
__device__ __forceinline__ float fast_acos(float x) {
    float ax = fabsf(x);
    float p = fmaf(ax, -0.0187293f, 0.0742610f);
    p = fmaf(ax, p, -0.2121144f);
    p = fmaf(ax, p, 1.5707288f);
    float pos = fsqrt(1.f - ax) * p;
    return x >= 0.f ? pos : PI_F - pos;
}

// v: 3x3 row-major (clipped). Columns: c0=(v0,v3,v6), c1=(v1,v4,v7), c2=(v2,v5,v8).
// R: row-major rotation, columns e1,e2,e3 (e3 sign-fixed by det).
__device__ __forceinline__ void gs_rotmat(const float* v, float* R) {
    float c0x = v[0], c0y = v[3], c0z = v[6];
    float c1x = v[1], c1y = v[4], c1z = v[7];
    float c2x = v[2], c2y = v[5], c2z = v[8];

    float s1 = fmaf(c0x, c0x, fmaf(c0y, c0y, c0z*c0z));
    float inv1 = frcp(fsqrt(s1) + EPS_GS);
    float e1x = c0x*inv1, e1y = c0y*inv1, e1z = c0z*inv1;

    float d = fmaf(e1x, c1x, fmaf(e1y, c1y, e1z*c1z));
    float u2x = fmaf(-d, e1x, c1x), u2y = fmaf(-d, e1y, c1y), u2z = fmaf(-d, e1z, c1z);
    float s2 = fmaf(u2x, u2x, fmaf(u2y, u2y, u2z*u2z));
    float inv2 = frcp(fsqrt(s2) + EPS_GS);
    float e2x = u2x*inv2, e2y = u2y*inv2, e2z = u2z*inv2;

    float d1 = fmaf(e1x, c2x, fmaf(e1y, c2y, e1z*c2z));
    float d2 = fmaf(e2x, c2x, fmaf(e2y, c2y, e2z*c2z));
    float u3x = fmaf(-d1, e1x, fmaf(-d2, e2x, c2x));
    float u3y = fmaf(-d1, e1y, fmaf(-d2, e2y, c2y));
    float u3z = fmaf(-d1, e1z, fmaf(-d2, e2z, c2z));
    float s3 = fmaf(u3x, u3x, fmaf(u3y, u3y, u3z*u3z));
    float inv3 = frcp(fsqrt(s3) + EPS_GS);
    float e3x = u3x*inv3, e3y = u3y*inv3, e3z = u3z*inv3;

    // det(Q) = e1 . (e2 x e3)
    float cxx = e2y*e3z - e2z*e3y;
    float cxy = e2z*e3x - e2x*e3z;
    float cxz = e2x*e3y - e2y*e3x;
    float det = fmaf(e1x, cxx, fmaf(e1y, cxy, e1z*cxz));
    if (det < 0.f) { e3x = -e3x; e3y = -e3y; e3z = -e3z; } // NaN<0 false -> keep

    R[0] = e1x; R[1] = e2x; R[2] = e3x;
    R[3] = e1y; R[4] = e2y; R[5] = e3y;
    R[6] = e1z; R[7] = e2z; R[8] = e3z;
}

__device__ __forceinline__ void accum_rot(const float* pr, const float* tg,
                                          float& lt, float& lf) {
    float pc[9], tc[9];
    #pragma unroll
    for (int m = 0; m < 9; ++m) { pc[m] = clip10(pr[m]); tc[m] = clip10(tg[m]); }

    float Rp[9], Rt[9];
    gs_rotmat(pc, Rp);
    gs_rotmat(tc, Rt);

    float chord = 0.f, tr = 0.f;
    #pragma unroll
    for (int m = 0; m < 9; ++m) {
        float d = Rp[m] - Rt[m];
        chord = fmaf(d, d, chord);
        tr    = fmaf(Rp[m], Rt[m], tr);
    }

    const float trLo = -3.0f + 1e-6f, trHi = 3.0f - 1e-6f;
    tr = tr < trLo ? trLo : (tr > trHi ? trHi : tr);
    float ca = (tr - 1.f) * 0.5f;
    const float cLo = -1.0f + 1e-7f, cHi = 1.0f - 1e-7f;
    ca = ca < cLo ? cLo : (ca > cHi ? cHi : ca);
    float ang = fast_acos(ca) * RAD2DEG;
    if (ang != ang) ang = 180.f;

    // orthogonality: AtA[i][j] = col_i . col_j of clipped pred matrix.
    // AtA symmetric: diag once, off-diag counted twice.
    float o = 0.f;
    #pragma unroll
    for (int i = 0; i < 3; ++i) {
        float dii = fmaf(pc[i], pc[i], fmaf(pc[3+i], pc[3+i], pc[6+i]*pc[6+i])) - 1.f;
        o = fmaf(dii, dii, o);
    }
    #pragma unroll
    for (int i = 0; i < 3; ++i) {
        #pragma unroll
        for (int j = i + 1; j < 3; ++j) {
            float s = fmaf(pc[i], pc[j], fmaf(pc[3+i], pc[3+j], pc[6+i]*pc[6+j]));
            float s2 = s + s;
            o = fmaf(s2, s, o);
        }
    }

    float l2 = 0.f, fb = 0.f;
    #pragma unroll
    for (int m = 0; m < 9; ++m) {
        l2 = fmaf(pc[m], pc[m], l2);
        float d = pc[m] - tg[m];   // fallback uses UNclipped target
        fb = fmaf(d, d, fb);
    }

    lt += fmaf(0.1f, ang, chord) + fmaf(0.01f, o, (1e-4f/9.f)*l2);
    lf += fb;
}

// Double-buffered LDS pipeline with async global->LDS staging (zero VGPR cost —
// r3's register prefetch was spilled to scratch: WRITE_SIZE 304MB). Per tile:
// issue next tile's 9 global_load_lds per wave -> s_waitcnt vmcnt(9) (current
// tile's loads retired, next tile's stay IN FLIGHT across the barrier) -> raw
// s_barrier -> compute from LDS -> raw s_barrier. No __syncthreads in the loop
// (it would drain vmcnt(0) and serialize the pipeline).
__global__ __launch_bounds__(THREADS, 2)
void rot_loss_kernel(const float* __restrict__ pred, const float* __restrict__ targ,
                     double* __restrict__ acc, int B) {
    __shared__ float buf[2][TILE_TOT];   // [0..TILE_F) pred, [TILE_F..) targ
    __shared__ float rsum_t[4], rsum_f[4];

    const int tid    = threadIdx.x;
    const int wv     = tid >> 6;          // wave id 0..3 (uniform within wave)
    const int lane   = tid & 63;
    const int ntiles = (B + TILE_ROTS - 1) / TILE_ROTS;
    const int tstep  = gridDim.x;

    float lt = 0.f, lf = 0.f;

    auto tile_full = [&](int t) {
        return (size_t)(t + 1) * TILE_ROTS <= (size_t)B;
    };
    // stage tile t into buf[b]: 36 chunks of 256 floats; wave wv takes chunks
    // wv, wv+4, ..., wv+32. Chunk c<18 comes from pred, else targ. All address
    // math is wave-uniform except the +lane*4 on the global side.
    auto stage = [&](int b, int t) {
        const float* psrc = pred + (size_t)t * TILE_F;
        const float* qsrc = targ + (size_t)t * TILE_F;
        #pragma unroll
        for (int k = 0; k < CH_PER_W; ++k) {
            const int c = wv + 4*k;
            const float* src = (c < 18) ? (psrc + (size_t)c * CHUNK_F)
                                        : (qsrc + (size_t)(c - 18) * CHUNK_F);
            gload_lds16(src + lane*4, &buf[b][c * CHUNK_F]);
        }
    };

    const int t0 = blockIdx.x;
    int cur = 0;
    if (t0 < ntiles && tile_full(t0)) stage(0, t0);   // prologue prefetch

    for (int t = t0; t < ntiles; t += tstep) {
        if (tile_full(t)) {
            const int tn = t + tstep;
            const bool nx = (tn < ntiles) && tile_full(tn);
            if (nx) {
                stage(cur ^ 1, tn);                         // +9 in flight
                asm volatile("s_waitcnt vmcnt(9)" ::: "memory");  // cur's 9 done
            } else {
                asm volatile("s_waitcnt vmcnt(0)" ::: "memory");
            }
            __builtin_amdgcn_s_barrier();        // all waves' chunks landed
            asm volatile("" ::: "memory");       // no ds_read hoists above this
            #pragma unroll
            for (int rr = 0; rr < 2; ++rr) {
                const int r = tid + rr*THREADS;
                accum_rot(&buf[cur][9*r], &buf[cur][TILE_F + 9*r], lt, lf);
            }
            asm volatile("" ::: "memory");       // no ds_read sinks below this
            __builtin_amdgcn_s_barrier();        // cur free for overwrite
            cur ^= 1;
        } else {
            // partial tail tile: direct loads, correctness only
            const size_t rot0 = (size_t)t * TILE_ROTS;
            const int rem = (int)((size_t)B - rot0);
            for (int r = tid; r < rem; r += THREADS) {
                float a1[9], b1[9];
                const float* pp = pred + (rot0 + r) * 9;
                const float* qq = targ + (rot0 + r) * 9;
                for (int m = 0; m < 9; ++m) { a1[m] = pp[m]; b1[m] = qq[m]; }
                accum_rot(a1, b1, lt, lf);
            }
        }
    }

    // wave-64 reduce
    #pragma unroll
    for (int off = 32; off > 0; off >>= 1) {
        lt += __shfl_down(lt, off, 64);
        lf += __shfl_down(lf, off, 64);
    }
    if (lane == 0) { rsum_t[wv] = lt; rsum_f[wv] = lf; }
    __syncthreads();
    if (tid == 0) {
        float bt = rsum_t[0] + rsum_t[1] + rsum_t[2] + rsum_t[3];
        float bf = rsum_f[0] + rsum_f[1] + rsum_f[2] + rsum_f[3];
        // spread atomics over 16 cache-line-strided slots to avoid
        // same-address f64 atomic serialization at the coherence point
        double* slot = acc + (size_t)(blockIdx.x & (NSLOTS - 1)) * 8;
        unsafeAtomicAdd(&slot[0], (double)bt);  // HW global_atomic_add_f64
        unsafeAtomicAdd(&slot[1], (double)bf);
    }
}

__global__ void finalize_kernel(const double* __restrict__ acc,
                                float* __restrict__ out, int B) {
    if (threadIdx.x == 0 && blockIdx.x == 0) {
        double t = 0.0, f = 0.0;
        for (int s = 0; s < NSLOTS; ++s) { t += acc[s*8]; f += acc[s*8 + 1]; }
        double total = t / (double)B;
        double fb    = f / (9.0 * (double)B);
        out[0] = isnan(total) ? (float)fb : (float)total;
    }
}

extern "C" void kernel_launch(void* const* d_in, const int* in_sizes, int n_in,
                              void* d_out, int out_size, void* d_ws, size_t ws_size,
                              hipStream_t stream) {
    const float* pred = (const float*)d_in[0];
    const float* targ = (const float*)d_in[1];
    const int n = in_sizes[0];
    const int B = n / 9;

    double* acc = (double*)d_ws;
    hipMemsetAsync(d_ws, 0, NSLOTS * 8 * sizeof(double), stream);

    const int ntiles = (B + TILE_ROTS - 1) / TILE_ROTS;
    const int blocks = ntiles < MAX_BLKS ? ntiles : MAX_BLKS;
    rot_loss_kernel<<<blocks, THREADS, 0, stream>>>(pred, targ, acc, B);
    finalize_kernel<<<1, 64, 0, stream>>>(acc, (float*)d_out, B);
}

// Round 5
// 312.180 us; speedup vs baseline: 1.2136x; 1.0152x over previous
//
#include <hip/hip_runtime.h>
#include <math.h>

#define EPS_GS 1e-8f
#define RAD2DEG 57.29577951308232f
#define PI_F 3.14159265358979f

constexpr int THREADS   = 256;
constexpr int TILE_ROTS = 256;                    // rotations per tile (1/thread)
constexpr int TILE_F    = TILE_ROTS * 9;          // 2304 floats = 9216 B per array
constexpr int TILE_TOT  = TILE_F * 2;             // pred+targ = 4608 floats / tile
constexpr int CHUNK_F   = 256;                    // floats per 1024B chunk (64 lanes x 16B)
constexpr int CHUNKS    = TILE_TOT / CHUNK_F;     // 18 chunks per tile (9 pred, 9 targ)
constexpr int NSLOTS    = 16;                     // atomic spread slots (64B stride)
constexpr int MAX_BLKS  = 1024;                   // 4 resident blocks x 256 CUs

__device__ __forceinline__ float clip10(float x) {
    // ternary form preserves NaN (matches jnp.clip NaN propagation)
    x = x < -10.f ? -10.f : x;
    x = x >  10.f ?  10.f : x;
    return x;
}

// v_sqrt_f32 / v_rcp_f32 — ~1 ulp, single-instruction
__device__ __forceinline__ float fsqrt(float x) { return __builtin_amdgcn_sqrtf(x); }
__device__ __forceinline__ float frcp(float x)  { return __builtin_amdgcn_rcpf(x); }

// async global->LDS, 16B per lane. LDS dest = wave-uniform base + lane*16.
__device__ __forceinline__ void gload_lds16(const float* g, float* l) {
    __builtin_amdgcn_global_load_lds(
        (const __attribute__((address_space(1))) void*)g,
        (__attribute__((address_space(3))) void*)l,
        16, 0, 0);
}

// Abramowitz-Stegun 4.4.45: max error 6.76e-5 rad on [-1,1]
__device__ __forceinline__ float fast_acos(float x) {
    float ax = fabsf(x);
    float p = fmaf(ax, -0.0187293f, 0.0742610f);
    p = fmaf(ax, p, -0.2121144f);
    p = fmaf(ax, p, 1.5707288f);
    float pos = fsqrt(1.f - ax) * p;
    return x >= 0.f ? pos : PI_F - pos;
}

// v: 3x3 row-major (clipped). Columns: c0=(v0,v3,v6), c1=(v1,v4,v7), c2=(v2,v5,v8).
// R: row-major rotation, columns e1,e2,e3 (e3 sign-fixed by det).
__device__ __forceinline__ void gs_rotmat(const float* v, float* R) {
    float c0x = v[0], c0y = v[3], c0z = v[6];
    float c1x = v[1], c1y = v[4], c1z = v[7];
    float c2x = v[2], c2y = v[5], c2z = v[8];

    float s1 = fmaf(c0x, c0x, fmaf(c0y, c0y, c0z*c0z));
    float inv1 = frcp(fsqrt(s1) + EPS_GS);
    float e1x = c0x*inv1, e1y = c0y*inv1, e1z = c0z*inv1;

    float d = fmaf(e1x, c1x, fmaf(e1y, c1y, e1z*c1z));
    float u2x = fmaf(-d, e1x, c1x), u2y = fmaf(-d, e1y, c1y), u2z = fmaf(-d, e1z, c1z);
    float s2 = fmaf(u2x, u2x, fmaf(u2y, u2y, u2z*u2z));
    float inv2 = frcp(fsqrt(s2) + EPS_GS);
    float e2x = u2x*inv2, e2y = u2y*inv2, e2z = u2z*inv2;

    float d1 = fmaf(e1x, c2x, fmaf(e1y, c2y, e1z*c2z));
    float d2 = fmaf(e2x, c2x, fmaf(e2y, c2y, e2z*c2z));
    float u3x = fmaf(-d1, e1x, fmaf(-d2, e2x, c2x));
    float u3y = fmaf(-d1, e1y, fmaf(-d2, e2y, c2y));
    float u3z = fmaf(-d1, e1z, fmaf(-d2, e2z, c2z));
    float s3 = fmaf(u3x, u3x, fmaf(u3y, u3y, u3z*u3z));
    float inv3 = frcp(fsqrt(s3) + EPS_GS);
    float e3x = u3x*inv3, e3y = u3y*inv3, e3z = u3z*inv3;

    // det(Q) = e1 . (e2 x e3)
    float cxx = e2y*e3z - e2z*e3y;
    float cxy = e2z*e3x - e2x*e3z;
    float cxz = e2x*e3y - e2y*e3x;
    float det = fmaf(e1x, cxx, fmaf(e1y, cxy, e1z*cxz));
    if (det < 0.f) { e3x = -e3x; e3y = -e3y; e3z = -e3z; } // NaN<0 false -> keep

    R[0] = e1x; R[1] = e2x; R[2] = e3x;
    R[3] = e1y; R[4] = e2y; R[5] = e3y;
    R[6] = e1z; R[7] = e2z; R[8] = e3z;
}

__device__ __forceinline__ void accum_rot(const float* pr, const float* tg,
                                          float& lt, float& lf) {
    float pc[9], tc[9];
    #pragma unroll
    for (int m = 0; m < 9; ++m) { pc[m] = clip10(pr[m]); tc[m] = clip10(tg[m]); }

    float Rp[9], Rt[9];
    gs_rotmat(pc, Rp);
    gs_rotmat(tc, Rt);

    float chord = 0.f, tr = 0.f;
    #pragma unroll
    for (int m = 0; m < 9; ++m) {
        float d = Rp[m] - Rt[m];
        chord = fmaf(d, d, chord);
        tr    = fmaf(Rp[m], Rt[m], tr);
    }

    const float trLo = -3.0f + 1e-6f, trHi = 3.0f - 1e-6f;
    tr = tr < trLo ? trLo : (tr > trHi ? trHi : tr);
    float ca = (tr - 1.f) * 0.5f;
    const float cLo = -1.0f + 1e-7f, cHi = 1.0f - 1e-7f;
    ca = ca < cLo ? cLo : (ca > cHi ? cHi : ca);
    float ang = fast_acos(ca) * RAD2DEG;
    if (ang != ang) ang = 180.f;

    // orthogonality: AtA[i][j] = col_i . col_j of clipped pred matrix.
    // AtA symmetric: diag once, off-diag counted twice.
    float o = 0.f;
    #pragma unroll
    for (int i = 0; i < 3; ++i) {
        float dii = fmaf(pc[i], pc[i], fmaf(pc[3+i], pc[3+i], pc[6+i]*pc[6+i])) - 1.f;
        o = fmaf(dii, dii, o);
    }
    #pragma unroll
    for (int i = 0; i < 3; ++i) {
        #pragma unroll
        for (int j = i + 1; j < 3; ++j) {
            float s = fmaf(pc[i], pc[j], fmaf(pc[3+i], pc[3+j], pc[6+i]*pc[6+j]));
            float s2 = s + s;
            o = fmaf(s2, s, o);
        }
    }

    float l2 = 0.f, fb = 0.f;
    #pragma unroll
    for (int m = 0; m < 9; ++m) {
        l2 = fmaf(pc[m], pc[m], l2);
        float d = pc[m] - tg[m];   // fallback uses UNclipped target
        fb = fmaf(d, d, fb);
    }

    lt += fmaf(0.1f, ang, chord) + fmaf(0.01f, o, (1e-4f/9.f)*l2);
    lf += fb;
}

// Async double-buffered pipeline at 4 blocks/CU (r4 lesson: the pipeline at
// 2 waves/SIMD = unpipelined at 4 waves/SIMD = 121us; need BOTH). 36.9 KB LDS
// -> 4 blocks/CU -> 4 waves/SIMD to hide accum_rot's ~1K-cycle serial chain.
// 18 chunks / 4 waves: waves 0-1 stage 5 chunks, waves 2-3 stage 4; each wave
// waits only its OWN outstanding count (branched vmcnt literal), so next tile's
// loads stay in flight across the barrier.
__global__ __launch_bounds__(THREADS, 4)
void rot_loss_kernel(const float* __restrict__ pred, const float* __restrict__ targ,
                     double* __restrict__ acc, int B) {
    __shared__ float buf[2][TILE_TOT];   // [0..TILE_F) pred, [TILE_F..) targ
    __shared__ float rsum_t[4], rsum_f[4];

    const int tid    = threadIdx.x;
    const int wv     = tid >> 6;          // wave id 0..3 (uniform within wave)
    const int lane   = tid & 63;
    const int ntiles = (B + TILE_ROTS - 1) / TILE_ROTS;
    const int tstep  = gridDim.x;

    float lt = 0.f, lf = 0.f;

    auto tile_full = [&](int t) {
        return (size_t)(t + 1) * TILE_ROTS <= (size_t)B;
    };
    // stage tile t into buf[b]: 18 chunks of 256 floats. Chunk c<9 from pred,
    // else targ. Waves 0,1 take chunks [5wv,5wv+5); waves 2,3 take [10+4(wv-2),+4).
    auto stage = [&](int b, int t) {
        const float* psrc = pred + (size_t)t * TILE_F;
        const float* qsrc = targ + (size_t)t * TILE_F;
        if (wv < 2) {
            #pragma unroll
            for (int k = 0; k < 5; ++k) {
                const int c = wv*5 + k;
                const float* src = (c < 9) ? (psrc + (size_t)c * CHUNK_F)
                                           : (qsrc + (size_t)(c - 9) * CHUNK_F);
                gload_lds16(src + lane*4, &buf[b][c * CHUNK_F]);
            }
        } else {
            #pragma unroll
            for (int k = 0; k < 4; ++k) {
                const int c = 10 + (wv-2)*4 + k;
                const float* src = (c < 9) ? (psrc + (size_t)c * CHUNK_F)
                                           : (qsrc + (size_t)(c - 9) * CHUNK_F);
                gload_lds16(src + lane*4, &buf[b][c * CHUNK_F]);
            }
        }
    };

    const int t0 = blockIdx.x;
    int cur = 0;
    if (t0 < ntiles && tile_full(t0)) stage(0, t0);   // prologue prefetch

    for (int t = t0; t < ntiles; t += tstep) {
        if (tile_full(t)) {
            const int tn = t + tstep;
            const bool nx = (tn < ntiles) && tile_full(tn);
            if (nx) {
                stage(cur ^ 1, tn);                   // next tile in flight
                // wait current tile's own loads only (wave-uniform branch)
                if (wv < 2) asm volatile("s_waitcnt vmcnt(5)" ::: "memory");
                else        asm volatile("s_waitcnt vmcnt(4)" ::: "memory");
            } else {
                asm volatile("s_waitcnt vmcnt(0)" ::: "memory");
            }
            __builtin_amdgcn_s_barrier();        // all waves' chunks landed
            asm volatile("" ::: "memory");       // no ds_read hoists above this
            accum_rot(&buf[cur][9*tid], &buf[cur][TILE_F + 9*tid], lt, lf);
            asm volatile("" ::: "memory");       // no ds_read sinks below this
            __builtin_amdgcn_s_barrier();        // cur free for overwrite
            cur ^= 1;
        } else {
            // partial tail tile: direct loads, correctness only
            const size_t rot0 = (size_t)t * TILE_ROTS;
            const int rem = (int)((size_t)B - rot0);
            for (int r = tid; r < rem; r += THREADS) {
                float a1[9], b1[9];
                const float* pp = pred + (rot0 + r) * 9;
                const float* qq = targ + (rot0 + r) * 9;
                for (int m = 0; m < 9; ++m) { a1[m] = pp[m]; b1[m] = qq[m]; }
                accum_rot(a1, b1, lt, lf);
            }
        }
    }

    // wave-64 reduce
    #pragma unroll
    for (int off = 32; off > 0; off >>= 1) {
        lt += __shfl_down(lt, off, 64);
        lf += __shfl_down(lf, off, 64);
    }
    if (lane == 0) { rsum_t[wv] = lt; rsum_f[wv] = lf; }
    __syncthreads();
    if (tid == 0) {
        float bt = rsum_t[0] + rsum_t[1] + rsum_t[2] + rsum_t[3];
        float bf = rsum_f[0] + rsum_f[1] + rsum_f[2] + rsum_f[3];
        // spread atomics over 16 cache-line-strided slots to avoid
        // same-address f64 atomic serialization at the coherence point
        double* slot = acc + (size_t)(blockIdx.x & (NSLOTS - 1)) * 8;
        unsafeAtomicAdd(&slot[0], (double)bt);  // HW global_atomic_add_f64
        unsafeAtomicAdd(&slot[1], (double)bf);
    }
}

__global__ void finalize_kernel(const double* __restrict__ acc,
                                float* __restrict__ out, int B) {
    if (threadIdx.x == 0 && blockIdx.x == 0) {
        double t = 0.0, f = 0.0;
        for (int s = 0; s < NSLOTS; ++s) { t += acc[s*8]; f += acc[s*8 + 1]; }
        double total = t / (double)B;
        double fb    = f / (9.0 * (double)B);
        out[0] = isnan(total) ? (float)fb : (float)total;
    }
}

extern "C" void kernel_launch(void* const* d_in, const int* in_sizes, int n_in,
                              void* d_out, int out_size, void* d_ws, size_t ws_size,
                              hipStream_t stream) {
    const float* pred = (const float*)d_in[0];
    const float* targ = (const float*)d_in[1];
    const int n = in_sizes[0];
    const int B = n / 9;

    double* acc = (double*)d_ws;
    hipMemsetAsync(d_ws, 0, NSLOTS * 8 * sizeof(double), stream);

    const int ntiles = (B + TILE_ROTS - 1) / TILE_ROTS;
    const int blocks = ntiles < MAX_BLKS ? ntiles : MAX_BLKS;
    rot_loss_kernel<<<blocks, THREADS, 0, stream>>>(pred, targ, acc, B);
    finalize_kernel<<<1, 64, 0, stream>>>(acc, (float*)d_out, B);
}